// Round 9
// baseline (162.385 us; speedup 1.0000x reference)
//
#include <hip/hip_runtime.h>

// LSTM: HIDDEN=128, SEQ=7, BATCH=65536. fp32 in/out.
//
// R16: occupancy fix. R15 post-mortem: VGPR 80 + AGPR 64 (bw frags) = 144
// unified regs -> only ONE 8-wave block/CU resident (Occupancy 21.5%) ->
// 2 waves/SIMD, barrier every timestep, ~80% pipe-idle. Weight-stationary
// pins 64 regs/lane, so cut TRANSIENT pressure instead:
//  * BT=32 (was 64), same 8 waves: each wave keeps its 16-hcol slice but
//    owns 2 row-tiles (mt=0,1). c2 16->8 regs, mt-loop transients halved.
//    Peak ~120 <= 128 -> 2 blocks/CU, 16 waves/CU, 2 independent barrier
//    domains per CU (block A's barrier/trans idle filled by block B).
//  * LDS 26KB/block (x2 = 52KB), grid 2048.
// Unchanged: weight-stationary B-frags, MFMA-pred side column (Wo LDS),
// bias folded into MFMA C-init, packed-f32 exp2 fused-reciprocal epilogue
// (R15-verified), fp16 h dbuf LDS, 1 barrier/t, (512,2).

#define SEQ 7
#define BT 32

typedef _Float16 half8 __attribute__((ext_vector_type(8)));
typedef float floatx4 __attribute__((ext_vector_type(4)));
typedef float floatx2 __attribute__((ext_vector_type(2)));

__device__ __forceinline__ floatx4 mfma16(half8 a, half8 b, floatx4 c) {
  return __builtin_amdgcn_mfma_f32_16x16x32_f16(a, b, c, 0, 0, 0);
}

#define LOG2E 1.4426950408889634f
#define K2 2.885390081777927f  // 2*log2e

// packed helpers: exp2(-v) and rcp(v), scalar trans ops on both halves
__device__ __forceinline__ floatx2 pexp2m(floatx2 v) {
  floatx2 r;
  r.x = __builtin_amdgcn_exp2f(-v.x);
  r.y = __builtin_amdgcn_exp2f(-v.y);
  return r;
}
__device__ __forceinline__ floatx2 prcp(floatx2 v) {
  floatx2 r;
  r.x = __builtin_amdgcn_rcpf(v.x);
  r.y = __builtin_amdgcn_rcpf(v.y);
  return r;
}

// Pack W_hh [512][128] fp32 -> B-fragment-major fp16, prescaled (idx<65536):
//   Bp[((nt*4+kk)*64 + lane)*8 + jj] = S(g) * Whh[j][k]
//   nt=g*8+w, j=g*128+w*16+col, k=32kk+8quad+jj (B-layout: lane kq*16+col
//   holds B[k=kq*8+jj][n=col] -- R7-proven).
// idx in [65536, 69632): W_out hi/lo fragments, col-0-only 16-col tile.
__global__ void pack_kernel(const float* __restrict__ Whh,
                            const float* __restrict__ Wout,
                            _Float16* __restrict__ Bp) {
  int idx = blockIdx.x * 256 + threadIdx.x;  // 0..69631
  if (idx < 65536) {
    int jj = idx & 7;
    int lane = (idx >> 3) & 63;
    int kk = (idx >> 9) & 3;
    int nt = idx >> 11;  // 0..31
    int g = nt >> 3, w = nt & 7;
    int col = lane & 15, quad = lane >> 4;
    int j = g * 128 + w * 16 + col;
    int k = 32 * kk + 8 * quad + jj;
    float S = (g == 2) ? K2 : LOG2E;
    Bp[idx] = (_Float16)(S * Whh[j * 128 + k]);
  } else {
    int pos = idx - 65536;  // 0..4095
    int hl = pos >> 11;     // 0 = hi, 1 = lo
    int e = pos & 2047;
    int jj = e & 7;
    int lane = (e >> 3) & 63;
    int kk = e >> 9;
    int col = lane & 15, quad = lane >> 4;
    int k = 32 * kk + 8 * quad + jj;
    float wv = Wout[k];
    _Float16 hi = (_Float16)wv;
    _Float16 v = hl ? (_Float16)(wv - (float)hi) : hi;
    Bp[idx] = (col == 0) ? v : (_Float16)0.0f;
  }
}

__launch_bounds__(512, 2)
__global__ void lstm_kernel(const float* __restrict__ x,
                            const float* __restrict__ x0,
                            const float* __restrict__ Wih,
                            const float* __restrict__ bih,
                            const float* __restrict__ bhh,
                            const float* __restrict__ boutp,
                            const _Float16* __restrict__ Bp,
                            float* __restrict__ out) {
  // h staged fp16, double-buffered, 272B row stride (+8 pad).
  __shared__ _Float16 Ah[2][BT][136];  // 17,408 B
  __shared__ float xs[2][BT];          // 256 B
  __shared__ _Float16 Wo[4096];        // 8 KB W_out hi/lo B-fragments

  const int tid = threadIdx.x;
  const int w = tid >> 6;  // wave 0..7: owns hcols [16w, 16w+16)
  const int lane = tid & 63;
  const int col = lane & 15;
  const int quad = lane >> 4;
  const int rowbase = blockIdx.x * BT;

  // stage W_out fragments into LDS (512 x 16B)
  if (tid < 512) ((half8*)Wo)[tid] = ((const half8*)(Bp + 65536))[tid];

  // Gate-GEMM weight fragments: 64 regs, loaded once for all timesteps.
  half8 bw[4][4];
#pragma unroll
  for (int g = 0; g < 4; ++g)
#pragma unroll
    for (int kk = 0; kk < 4; ++kk)
      bw[g][kk] =
          *(const half8*)(Bp + (((g * 8 + w) * 4 + kk) * 64 + lane) * 8);

  // Per-lane epilogue constants, gate-col j = g*128 + 16w + col.
  float wih_r[4], bias_r[4];
#pragma unroll
  for (int g = 0; g < 4; ++g) {
    int j = g * 128 + w * 16 + col;
    float S = (g == 2) ? K2 : LOG2E;
    wih_r[g] = S * Wih[j];
    bias_r[g] = S * (bih[j] + bhh[j]);
  }
  const float bout = boutp[0];

  const floatx2 one2 = {1.0f, 1.0f};
  const floatx2 k22 = {K2, K2};

  // Scaled cell state c~ = 2log2e*c, pair-major float2 -> 8 registers.
  floatx2 c2[2][2];
#pragma unroll
  for (int mt = 0; mt < 2; ++mt)
#pragma unroll
    for (int p = 0; p < 2; ++p) c2[mt][p] = (floatx2){0.f, 0.f};

  if (tid < BT) xs[0][tid] = x0[rowbase + tid];  // t=0 consumes x0
  __syncthreads();

#pragma unroll 1
  for (int t = 0; t < SEQ; ++t) {
    const int cur = t & 1, nxt = cur ^ 1;

    // prefetch input for t+1 (consumes x[:, t])
    if (t + 1 < SEQ && tid < BT) {
      xs[nxt][tid] = x[(size_t)(rowbase + tid) * 7 + t];
    }

#pragma unroll
    for (int mt = 0; mt < 2; ++mt) {
      // x for the 4 rows (mt*16 + quad*4 + r) this lane covers.
      floatx4 xq = *(const floatx4*)&xs[cur][mt * 16 + quad * 4];

      // acc init = x*W_ih + bias (prescaled) -> MFMA C operand.
      floatx4 acc[4];
#pragma unroll
      for (int g = 0; g < 4; ++g)
#pragma unroll
        for (int r = 0; r < 4; ++r)
          acc[g][r] = __builtin_fmaf(wih_r[g], xq[r], bias_r[g]);

      const bool dopred = (w < 2) && (mt == w);  // wave-uniform

      if (t != 0) {  // h(0)=0: skip GEMM at t=0
        floatx4 ap = (floatx4){0.f, 0.f, 0.f, 0.f};  // pred(t-1) partial
#pragma unroll
        for (int kk = 0; kk < 4; ++kk) {
          half8 ah =
              *(const half8*)&Ah[cur][mt * 16 + col][kk * 32 + quad * 8];
#pragma unroll
          for (int g = 0; g < 4; ++g) acc[g] = mfma16(ah, bw[g][kk], acc[g]);
          if (dopred) {  // wave preds its own row tile (full K in ah)
            half8 bo0 = *(const half8*)&Wo[(kk * 64 + lane) * 8];
            half8 bo1 = *(const half8*)&Wo[2048 + (kk * 64 + lane) * 8];
            ap = mfma16(ah, bo0, ap);
            ap = mfma16(ah, bo1, ap);
          }
        }
        if (dopred && col == 0) {
#pragma unroll
          for (int r = 0; r < 4; ++r)
            out[(size_t)(rowbase + mt * 16 + quad * 4 + r) * 7 + (t - 1)] =
                ap[r] + bout;
        }
      }

      // Fused-reciprocal cell update, PACKED pairs (r01, r23):
      //   A=2^-Gi', B=2^-Gf', C=2^-Gg'', D=2^-Go'
      //   c~' = [c~(1+A)(1+C) + K2(1-C)(1+B)] / [(1+A)(1+B)(1+C)]
      //   E = 2^-c~' ; h = (1-E)/[(1+D)(1+E)]
#pragma unroll
      for (int p = 0; p < 2; ++p) {
        floatx2 Gi, Gf, Gg, Go;
        Gi.x = acc[0][2 * p];
        Gi.y = acc[0][2 * p + 1];
        Gf.x = acc[1][2 * p];
        Gf.y = acc[1][2 * p + 1];
        Gg.x = acc[2][2 * p];
        Gg.y = acc[2][2 * p + 1];
        Go.x = acc[3][2 * p];
        Go.y = acc[3][2 * p + 1];
        floatx2 A = pexp2m(Gi);
        floatx2 Bv = pexp2m(Gf);
        floatx2 Cv = pexp2m(Gg);
        floatx2 Dv = pexp2m(Go);
        floatx2 a1 = A + one2;
        floatx2 b1 = Bv + one2;
        floatx2 c1 = Cv + one2;
        floatx2 ac = a1 * c1;
        floatx2 t1 = k22 - Cv * k22;
        floatx2 num = c2[mt][p] * ac + t1 * b1;
        floatx2 den = ac * b1;
        floatx2 cn = num * prcp(den);
        c2[mt][p] = cn;
        floatx2 E = pexp2m(cn);
        floatx2 de = (Dv + one2) * (E + one2);
        floatx2 hn = (one2 - E) * prcp(de);
        // stage h_new (fp16); lane owns hcol 16w+col; rows 2p, 2p+1
        Ah[nxt][mt * 16 + quad * 4 + 2 * p][w * 16 + col] = (_Float16)hn.x;
        Ah[nxt][mt * 16 + quad * 4 + 2 * p + 1][w * 16 + col] =
            (_Float16)hn.y;
      }
    }
    // single barrier per t: h staging + xs prefetch complete
    __syncthreads();
  }

  // tail: pred(6) from h(6) staged in Ah[1]
  if (w < 2) {
    const int mt = w;
    floatx4 ap = (floatx4){0.f, 0.f, 0.f, 0.f};
#pragma unroll
    for (int kk = 0; kk < 4; ++kk) {
      half8 ah = *(const half8*)&Ah[1][mt * 16 + col][kk * 32 + quad * 8];
      half8 bo0 = *(const half8*)&Wo[(kk * 64 + lane) * 8];
      half8 bo1 = *(const half8*)&Wo[2048 + (kk * 64 + lane) * 8];
      ap = mfma16(ah, bo0, ap);
      ap = mfma16(ah, bo1, ap);
    }
    if (col == 0) {
#pragma unroll
      for (int r = 0; r < 4; ++r)
        out[(size_t)(rowbase + mt * 16 + quad * 4 + r) * 7 + 6] =
            ap[r] + bout;
    }
  }
}

extern "C" void kernel_launch(void* const* d_in, const int* in_sizes, int n_in,
                              void* d_out, int out_size, void* d_ws,
                              size_t ws_size, hipStream_t stream) {
  const float* x = (const float*)d_in[0];
  const float* x0 = (const float*)d_in[1];
  const float* Wih = (const float*)d_in[2];
  const float* Whh = (const float*)d_in[3];
  const float* bih = (const float*)d_in[4];
  const float* bhh = (const float*)d_in[5];
  const float* Wout = (const float*)d_in[6];
  const float* bout = (const float*)d_in[7];
  float* out = (float*)d_out;
  _Float16* Bp = (_Float16*)d_ws;  // 136 KB packed weights + wout frags

  pack_kernel<<<272, 256, 0, stream>>>(Whh, Wout, Bp);
  lstm_kernel<<<65536 / BT, 512, 0, stream>>>(x, x0, Wih, bih, bhh, bout, Bp,
                                              out);
}

// Round 10
// 145.707 us; speedup vs baseline: 1.1145x; 1.1145x over previous
//
#include <hip/hip_runtime.h>

// LSTM: HIDDEN=128, SEQ=7, BATCH=65536. fp32 in/out.
//
// R17: occupancy fix, attempt 2. R16 post-mortem: 72 arch + 64 AGPR = 136
// unified regs > 128 -> still ONE 8-wave block/CU (21.9%); BT=32 alone just
// halved per-block work (100->110us). Also: R12 (140 regs, (512,2), NO
// spill) refutes blocks/CU launch-bounds semantics -- 2nd arg is min
// waves/EU (guide semantics): (512,2)=cap 256, (512,4)=cap 128.
//  * Fix 1: wih_r/bias_r (8 persistent regs) -> LDS table Twb[8][16][8],
//    read per-mt as VOLATILE float4 pairs (volatile blocks re-hoisting;
//    quad-uniform address -> broadcast, conflict-free). Demand -> ~128.
//  * Fix 2: __launch_bounds__(512,4) = cap 128 unified -> 2 blocks/CU,
//    16 waves/CU, two independent barrier domains per CU.
// Unchanged from R16: BT=32, weight-stationary bw in AGPRs, MFMA-pred
// side column (Wo LDS), packed-f32 exp2 fused-reciprocal epilogue,
// fp16 h dbuf LDS, 1 barrier/t.

#define SEQ 7
#define BT 32

typedef _Float16 half8 __attribute__((ext_vector_type(8)));
typedef float floatx4 __attribute__((ext_vector_type(4)));
typedef float floatx2 __attribute__((ext_vector_type(2)));

__device__ __forceinline__ floatx4 mfma16(half8 a, half8 b, floatx4 c) {
  return __builtin_amdgcn_mfma_f32_16x16x32_f16(a, b, c, 0, 0, 0);
}

#define LOG2E 1.4426950408889634f
#define K2 2.885390081777927f  // 2*log2e

// packed helpers: exp2(-v) and rcp(v), scalar trans ops on both halves
__device__ __forceinline__ floatx2 pexp2m(floatx2 v) {
  floatx2 r;
  r.x = __builtin_amdgcn_exp2f(-v.x);
  r.y = __builtin_amdgcn_exp2f(-v.y);
  return r;
}
__device__ __forceinline__ floatx2 prcp(floatx2 v) {
  floatx2 r;
  r.x = __builtin_amdgcn_rcpf(v.x);
  r.y = __builtin_amdgcn_rcpf(v.y);
  return r;
}

// Pack W_hh [512][128] fp32 -> B-fragment-major fp16, prescaled (idx<65536):
//   Bp[((nt*4+kk)*64 + lane)*8 + jj] = S(g) * Whh[j][k]
//   nt=g*8+w, j=g*128+w*16+col, k=32kk+8quad+jj (B-layout: lane kq*16+col
//   holds B[k=kq*8+jj][n=col] -- R7-proven).
// idx in [65536, 69632): W_out hi/lo fragments, col-0-only 16-col tile.
__global__ void pack_kernel(const float* __restrict__ Whh,
                            const float* __restrict__ Wout,
                            _Float16* __restrict__ Bp) {
  int idx = blockIdx.x * 256 + threadIdx.x;  // 0..69631
  if (idx < 65536) {
    int jj = idx & 7;
    int lane = (idx >> 3) & 63;
    int kk = (idx >> 9) & 3;
    int nt = idx >> 11;  // 0..31
    int g = nt >> 3, w = nt & 7;
    int col = lane & 15, quad = lane >> 4;
    int j = g * 128 + w * 16 + col;
    int k = 32 * kk + 8 * quad + jj;
    float S = (g == 2) ? K2 : LOG2E;
    Bp[idx] = (_Float16)(S * Whh[j * 128 + k]);
  } else {
    int pos = idx - 65536;  // 0..4095
    int hl = pos >> 11;     // 0 = hi, 1 = lo
    int e = pos & 2047;
    int jj = e & 7;
    int lane = (e >> 3) & 63;
    int kk = e >> 9;
    int col = lane & 15, quad = lane >> 4;
    int k = 32 * kk + 8 * quad + jj;
    float wv = Wout[k];
    _Float16 hi = (_Float16)wv;
    _Float16 v = hl ? (_Float16)(wv - (float)hi) : hi;
    Bp[idx] = (col == 0) ? v : (_Float16)0.0f;
  }
}

__launch_bounds__(512, 4)
__global__ void lstm_kernel(const float* __restrict__ x,
                            const float* __restrict__ x0,
                            const float* __restrict__ Wih,
                            const float* __restrict__ bih,
                            const float* __restrict__ bhh,
                            const float* __restrict__ boutp,
                            const _Float16* __restrict__ Bp,
                            float* __restrict__ out) {
  // h staged fp16, double-buffered, 272B row stride (+8 pad).
  __shared__ _Float16 Ah[2][BT][136];  // 17,408 B
  __shared__ float xs[2][BT];          // 256 B
  __shared__ _Float16 Wo[4096];        // 8 KB W_out hi/lo B-fragments
  __shared__ float Twb[8][16][8];      // 4 KB {wih[4], bias[4]} per (w,col)

  const int tid = threadIdx.x;
  const int w = tid >> 6;  // wave 0..7: owns hcols [16w, 16w+16)
  const int lane = tid & 63;
  const int col = lane & 15;
  const int quad = lane >> 4;
  const int rowbase = blockIdx.x * BT;

  // stage W_out fragments into LDS (512 x 16B)
  ((half8*)Wo)[tid] = ((const half8*)(Bp + 65536))[tid];

  // build the per-(w,col) prescaled wih/bias table
  if (tid < 128) {
    int tw = tid >> 4, tc = tid & 15;
#pragma unroll
    for (int g = 0; g < 4; ++g) {
      int j = g * 128 + tw * 16 + tc;
      float S = (g == 2) ? K2 : LOG2E;
      Twb[tw][tc][g] = S * Wih[j];
      Twb[tw][tc][4 + g] = S * (bih[j] + bhh[j]);
    }
  }

  // Gate-GEMM weight fragments: 64 regs, loaded once for all timesteps.
  half8 bw[4][4];
#pragma unroll
  for (int g = 0; g < 4; ++g)
#pragma unroll
    for (int kk = 0; kk < 4; ++kk)
      bw[g][kk] =
          *(const half8*)(Bp + (((g * 8 + w) * 4 + kk) * 64 + lane) * 8);

  const float bout = boutp[0];

  // Scaled cell state c~ = 2log2e*c, pair-major float2 -> 8 registers.
  floatx2 c2[2][2];
#pragma unroll
  for (int mt = 0; mt < 2; ++mt)
#pragma unroll
    for (int p = 0; p < 2; ++p) c2[mt][p] = (floatx2){0.f, 0.f};

  if (tid < BT) xs[0][tid] = x0[rowbase + tid];  // t=0 consumes x0
  __syncthreads();

#pragma unroll 1
  for (int t = 0; t < SEQ; ++t) {
    const int cur = t & 1, nxt = cur ^ 1;

    // prefetch input for t+1 (consumes x[:, t])
    if (t + 1 < SEQ && tid < BT) {
      xs[nxt][tid] = x[(size_t)(rowbase + tid) * 7 + t];
    }

#pragma unroll
    for (int mt = 0; mt < 2; ++mt) {
      // x for the 4 rows (mt*16 + quad*4 + r) this lane covers.
      floatx4 xq = *(const floatx4*)&xs[cur][mt * 16 + quad * 4];

      // wih/bias from LDS, volatile so they stay transient (no re-hoist);
      // quad-uniform address -> broadcast read, conflict-free.
      floatx4 wihv = *(volatile const floatx4*)&Twb[w][col][0];
      floatx4 biasv = *(volatile const floatx4*)&Twb[w][col][4];

      // acc init = x*W_ih + bias (prescaled) -> MFMA C operand.
      floatx4 acc[4];
#pragma unroll
      for (int g = 0; g < 4; ++g)
#pragma unroll
        for (int r = 0; r < 4; ++r)
          acc[g][r] = __builtin_fmaf(wihv[g], xq[r], biasv[g]);

      const bool dopred = (w < 2) && (mt == w);  // wave-uniform

      if (t != 0) {  // h(0)=0: skip GEMM at t=0
        floatx4 ap = (floatx4){0.f, 0.f, 0.f, 0.f};  // pred(t-1) partial
#pragma unroll
        for (int kk = 0; kk < 4; ++kk) {
          half8 ah =
              *(const half8*)&Ah[cur][mt * 16 + col][kk * 32 + quad * 8];
#pragma unroll
          for (int g = 0; g < 4; ++g) acc[g] = mfma16(ah, bw[g][kk], acc[g]);
          if (dopred) {  // wave preds its own row tile (full K in ah)
            half8 bo0 = *(const half8*)&Wo[(kk * 64 + lane) * 8];
            half8 bo1 = *(const half8*)&Wo[2048 + (kk * 64 + lane) * 8];
            ap = mfma16(ah, bo0, ap);
            ap = mfma16(ah, bo1, ap);
          }
        }
        if (dopred && col == 0) {
#pragma unroll
          for (int r = 0; r < 4; ++r)
            out[(size_t)(rowbase + mt * 16 + quad * 4 + r) * 7 + (t - 1)] =
                ap[r] + bout;
        }
      }

      // Fused-reciprocal cell update, PACKED pairs (r01, r23):
      //   A=2^-Gi', B=2^-Gf', C=2^-Gg'', D=2^-Go'
      //   c~' = [c~(1+A)(1+C) + K2(1-C)(1+B)] / [(1+A)(1+B)(1+C)]
      //   E = 2^-c~' ; h = (1-E)/[(1+D)(1+E)]
      const floatx2 one2 = {1.0f, 1.0f};
      const floatx2 k22 = {K2, K2};
#pragma unroll
      for (int p = 0; p < 2; ++p) {
        floatx2 Gi, Gf, Gg, Go;
        Gi.x = acc[0][2 * p];
        Gi.y = acc[0][2 * p + 1];
        Gf.x = acc[1][2 * p];
        Gf.y = acc[1][2 * p + 1];
        Gg.x = acc[2][2 * p];
        Gg.y = acc[2][2 * p + 1];
        Go.x = acc[3][2 * p];
        Go.y = acc[3][2 * p + 1];
        floatx2 A = pexp2m(Gi);
        floatx2 Bv = pexp2m(Gf);
        floatx2 Cv = pexp2m(Gg);
        floatx2 Dv = pexp2m(Go);
        floatx2 a1 = A + one2;
        floatx2 b1 = Bv + one2;
        floatx2 c1 = Cv + one2;
        floatx2 ac = a1 * c1;
        floatx2 t1 = k22 - Cv * k22;
        floatx2 num = c2[mt][p] * ac + t1 * b1;
        floatx2 den = ac * b1;
        floatx2 cn = num * prcp(den);
        c2[mt][p] = cn;
        floatx2 E = pexp2m(cn);
        floatx2 de = (Dv + one2) * (E + one2);
        floatx2 hn = (one2 - E) * prcp(de);
        // stage h_new (fp16); lane owns hcol 16w+col; rows 2p, 2p+1
        Ah[nxt][mt * 16 + quad * 4 + 2 * p][w * 16 + col] = (_Float16)hn.x;
        Ah[nxt][mt * 16 + quad * 4 + 2 * p + 1][w * 16 + col] =
            (_Float16)hn.y;
      }
    }
    // single barrier per t: h staging + xs prefetch complete
    __syncthreads();
  }

  // tail: pred(6) from h(6) staged in Ah[1]
  if (w < 2) {
    const int mt = w;
    floatx4 ap = (floatx4){0.f, 0.f, 0.f, 0.f};
#pragma unroll
    for (int kk = 0; kk < 4; ++kk) {
      half8 ah = *(const half8*)&Ah[1][mt * 16 + col][kk * 32 + quad * 8];
      half8 bo0 = *(const half8*)&Wo[(kk * 64 + lane) * 8];
      half8 bo1 = *(const half8*)&Wo[2048 + (kk * 64 + lane) * 8];
      ap = mfma16(ah, bo0, ap);
      ap = mfma16(ah, bo1, ap);
    }
    if (col == 0) {
#pragma unroll
      for (int r = 0; r < 4; ++r)
        out[(size_t)(rowbase + mt * 16 + quad * 4 + r) * 7 + 6] =
            ap[r] + bout;
    }
  }
}

extern "C" void kernel_launch(void* const* d_in, const int* in_sizes, int n_in,
                              void* d_out, int out_size, void* d_ws,
                              size_t ws_size, hipStream_t stream) {
  const float* x = (const float*)d_in[0];
  const float* x0 = (const float*)d_in[1];
  const float* Wih = (const float*)d_in[2];
  const float* Whh = (const float*)d_in[3];
  const float* bih = (const float*)d_in[4];
  const float* bhh = (const float*)d_in[5];
  const float* Wout = (const float*)d_in[6];
  const float* bout = (const float*)d_in[7];
  float* out = (float*)d_out;
  _Float16* Bp = (_Float16*)d_ws;  // 136 KB packed weights + wout frags

  pack_kernel<<<272, 256, 0, stream>>>(Whh, Wout, Bp);
  lstm_kernel<<<65536 / BT, 512, 0, stream>>>(x, x0, Wih, bih, bhh, bout, Bp,
                                              out);
}